// Round 2
// baseline (146999.878 us; speedup 1.0000x reference)
//
#include <hip/hip_runtime.h>
#include <cstdint>
#include <cstddef>

#define NEGV (-1e30f)

// Problem constants (fixed by setup_inputs):
//   B=64, N=256, IN=1024, HID=OUT=2048, BN = B*N = 16384
enum { EPI_STORE = 0, EPI_ADD = 1, EPI_BIAS_RELU = 2, EPI_BIAS_RELU_SCALE = 3,
       EPI_BIAS = 4, EPI_MASK_TAU = 5 };

// Generic fp32 GEMM: C[bz] = op( A[bz] (xT) @ B[bz] (xT) )
//  !TA: A is [M,K] row-major (lda=K).  TA: A is [K,M] row-major (lda=M) -> computes A^T @ B.
//  !TB: B is [K,N] row-major (ldb=N).  TB: B is [N,K] row-major (ldb=K) -> contracts over B cols.
// Tiles: 128x128 C-tile, K-step 8, 256 threads, 8x8 per thread.
// M, N divisible by 128; K divisible by 8.
template<bool TA, bool TB, int EPI>
__global__ __launch_bounds__(256, 2)
void sgemm_k(const float* __restrict__ Ab, const float* __restrict__ Bb,
             float* __restrict__ Cb, const int M, const int N, const int K,
             const long long sA, const long long sB, const long long sC,
             const float* __restrict__ bias, const float* __restrict__ rowscale,
             const int* __restrict__ n1p, const int* __restrict__ n2p,
             const int* __restrict__ taup)
{
    __shared__ float As[8][128];
    __shared__ float Bs[8][128];
    const int bz = blockIdx.z;
    const float* __restrict__ A = Ab + (size_t)bz * (size_t)sA;
    const float* __restrict__ B = Bb + (size_t)bz * (size_t)sB;
    float* __restrict__ C = Cb + (size_t)bz * (size_t)sC;
    const int lda = TA ? M : K;
    const int ldb = TB ? K : N;
    const int m0 = blockIdx.y * 128;
    const int n0 = blockIdx.x * 128;
    const int tid = (int)threadIdx.x;
    const int tx = tid & 15, ty = tid >> 4;

    float acc[8][8];
#pragma unroll
    for (int i = 0; i < 8; ++i)
#pragma unroll
        for (int j = 0; j < 8; ++j) acc[i][j] = 0.f;

    for (int k0 = 0; k0 < K; k0 += 8) {
        if constexpr (!TA) {
            const int r = tid >> 1, kq = (tid & 1) * 4;
            const float4 va = *(const float4*)(A + (size_t)(m0 + r) * lda + (k0 + kq));
            As[kq + 0][r] = va.x; As[kq + 1][r] = va.y;
            As[kq + 2][r] = va.z; As[kq + 3][r] = va.w;
        } else {
            const int kr = tid >> 5, mq = (tid & 31) * 4;
            *(float4*)&As[kr][mq] =
                *(const float4*)(A + (size_t)(k0 + kr) * lda + (m0 + mq));
        }
        if constexpr (!TB) {
            const int kr = tid >> 5, nq = (tid & 31) * 4;
            *(float4*)&Bs[kr][nq] =
                *(const float4*)(B + (size_t)(k0 + kr) * ldb + (n0 + nq));
        } else {
            const int r = tid >> 1, kq = (tid & 1) * 4;
            const float4 vb = *(const float4*)(B + (size_t)(n0 + r) * ldb + (k0 + kq));
            Bs[kq + 0][r] = vb.x; Bs[kq + 1][r] = vb.y;
            Bs[kq + 2][r] = vb.z; Bs[kq + 3][r] = vb.w;
        }
        __syncthreads();
#pragma unroll
        for (int kk = 0; kk < 8; ++kk) {
            float a[8], b[8];
            *(float4*)&a[0] = *(const float4*)&As[kk][ty * 8];
            *(float4*)&a[4] = *(const float4*)&As[kk][ty * 8 + 4];
            *(float4*)&b[0] = *(const float4*)&Bs[kk][tx * 8];
            *(float4*)&b[4] = *(const float4*)&Bs[kk][tx * 8 + 4];
#pragma unroll
            for (int i = 0; i < 8; ++i)
#pragma unroll
                for (int j = 0; j < 8; ++j)
                    acc[i][j] = fmaf(a[i], b[j], acc[i][j]);
        }
        __syncthreads();
    }

    int n1b = 0, n2b = 0; float tauv = 1.f;
    if constexpr (EPI == EPI_MASK_TAU) {
        n1b = n1p[bz]; n2b = n2p[bz]; tauv = (float)taup[0];
    }
    const int row0 = m0 + ty * 8;
    const int col0 = n0 + tx * 8;
#pragma unroll
    for (int i = 0; i < 8; ++i) {
        const int row = row0 + i;
        float rs = 1.f;
        if constexpr (EPI == EPI_BIAS_RELU_SCALE) rs = rowscale[row];
#pragma unroll
        for (int jj = 0; jj < 8; jj += 4) {
            float4 v = *(float4*)&acc[i][jj];
            const int col = col0 + jj;
            float* cp = C + (size_t)row * N + col;
            if constexpr (EPI == EPI_ADD) {
                const float4 o = *(const float4*)cp;
                v.x += o.x; v.y += o.y; v.z += o.z; v.w += o.w;
            } else if constexpr (EPI == EPI_BIAS_RELU || EPI == EPI_BIAS_RELU_SCALE) {
                const float4 bb = *(const float4*)(bias + col);
                v.x = fmaxf(v.x + bb.x, 0.f) * rs;
                v.y = fmaxf(v.y + bb.y, 0.f) * rs;
                v.z = fmaxf(v.z + bb.z, 0.f) * rs;
                v.w = fmaxf(v.w + bb.w, 0.f) * rs;
            } else if constexpr (EPI == EPI_BIAS) {
                const float4 bb = *(const float4*)(bias + col);
                v.x += bb.x; v.y += bb.y; v.z += bb.z; v.w += bb.w;
            } else if constexpr (EPI == EPI_MASK_TAU) {
                const bool rv = row < n1b;
                v.x = (rv && col + 0 < n2b) ? v.x / tauv : NEGV;
                v.y = (rv && col + 1 < n2b) ? v.y / tauv : NEGV;
                v.z = (rv && col + 2 < n2b) ? v.z / tauv : NEGV;
                v.w = (rv && col + 3 < n2b) ? v.w / tauv : NEGV;
            }
            *(float4*)cp = v;
        }
    }
}

// rcs[b,j] = 1 / max(sum_i |A[b,i,j]|, 1e-12)   (column L1 norms)
__global__ __launch_bounds__(256)
void colsum_rcp_k(const float* __restrict__ A, float* __restrict__ rcs)
{
    const int b = blockIdx.x, j = (int)threadIdx.x;
    const float* p = A + (size_t)b * 65536;
    float s = 0.f;
    for (int i = 0; i < 256; ++i) s += fabsf(p[i * 256 + j]);
    rcs[b * 256 + j] = 1.f / fmaxf(s, 1e-12f);
}

// Row logsumexp pass: one 64-lane wave per row (4 rows / block of 256).
__global__ __launch_bounds__(256)
void sk_row_k(float* __restrict__ S, const int* __restrict__ n1p)
{
    const int w = (int)threadIdx.x >> 6, lane = (int)threadIdx.x & 63;
    const int rowg = blockIdx.x * 4 + w;       // global row in [0, B*N)
    const int b = rowg >> 8, i = rowg & 255;
    float* p = S + (size_t)rowg * 256;
    float4 v = ((const float4*)p)[lane];
    float m = fmaxf(fmaxf(v.x, v.y), fmaxf(v.z, v.w));
#pragma unroll
    for (int off = 32; off > 0; off >>= 1) m = fmaxf(m, __shfl_down(m, off));
    m = __shfl(m, 0);
    float s = expf(v.x - m) + expf(v.y - m) + expf(v.z - m) + expf(v.w - m);
#pragma unroll
    for (int off = 32; off > 0; off >>= 1) s += __shfl_down(s, off);
    s = __shfl(s, 0);
    const float lse = m + logf(s);
    if (i < n1p[b]) {
        v.x -= lse; v.y -= lse; v.z -= lse; v.w -= lse;
        ((float4*)p)[lane] = v;
    }
}

// Column logsumexp pass: one block (1024 thr) per batch matrix.
__global__ __launch_bounds__(1024)
void sk_col_k(float* __restrict__ S, const int* __restrict__ n2p)
{
    __shared__ float Ms[4][256], Ss[4][256], Ls[256];
    const int b = blockIdx.x;
    const int j = (int)threadIdx.x & 255, q = (int)threadIdx.x >> 8;
    float* base = S + (size_t)b * 65536;
    float m = -3.0e38f;
    for (int i = q * 64; i < q * 64 + 64; ++i) m = fmaxf(m, base[i * 256 + j]);
    float s = 0.f;
    for (int i = q * 64; i < q * 64 + 64; ++i) s += expf(base[i * 256 + j] - m);
    Ms[q][j] = m; Ss[q][j] = s;
    __syncthreads();
    if (q == 0) {
        const float m0 = Ms[0][j], m1 = Ms[1][j], m2 = Ms[2][j], m3 = Ms[3][j];
        const float mm = fmaxf(fmaxf(m0, m1), fmaxf(m2, m3));
        const float ss = Ss[0][j] * expf(m0 - mm) + Ss[1][j] * expf(m1 - mm) +
                         Ss[2][j] * expf(m2 - mm) + Ss[3][j] * expf(m3 - mm);
        Ls[j] = mm + logf(ss);
    }
    __syncthreads();
    if (j < n2p[b]) {
        const float lse = Ls[j];
        for (int i = q * 64; i < q * 64 + 64; ++i) base[i * 256 + j] -= lse;
    }
}

// Final: out = mask ? exp(log_s) : 0   (in place)
__global__ __launch_bounds__(256)
void sk_exp_k(float* __restrict__ S, const int* __restrict__ n1p,
              const int* __restrict__ n2p)
{
    const size_t idx = (size_t)blockIdx.x * 256 + threadIdx.x;
    const int b = (int)(idx >> 16);
    const int i = (int)((idx >> 8) & 255), j = (int)(idx & 255);
    const float v = S[idx];
    S[idx] = (i < n1p[b] && j < n2p[b]) ? expf(v) : 0.f;
}

// float4 grid-stride copy (d2d, graph-capture-safe)
__global__ __launch_bounds__(256)
void copy4_k(const float4* __restrict__ s, float4* __restrict__ d, long long n4)
{
    long long i = (long long)blockIdx.x * 256 + threadIdx.x;
    const long long st = (long long)gridDim.x * 256;
    for (; i < n4; i += st) d[i] = s[i];
}

extern "C" void kernel_launch(void* const* d_in, const int* in_sizes, int n_in,
                              void* d_out, int out_size, void* d_ws, size_t ws_size,
                              hipStream_t stream)
{
    (void)in_sizes; (void)n_in; (void)out_size;
    const float* feat1  = (const float*)d_in[0];
    const float* feat2  = (const float*)d_in[1];
    const float* A1     = (const float*)d_in[2];
    const float* A2     = (const float*)d_in[3];
    const float* g0_aW  = (const float*)d_in[4];
    const float* g0_ab  = (const float*)d_in[5];
    const float* g0_uW  = (const float*)d_in[6];
    const float* g0_ub  = (const float*)d_in[7];
    const float* g1_aW  = (const float*)d_in[8];
    const float* g1_ab  = (const float*)d_in[9];
    const float* g1_uW  = (const float*)d_in[10];
    const float* g1_ub  = (const float*)d_in[11];
    const float* aff0_W = (const float*)d_in[12];
    const float* aff1_W = (const float*)d_in[13];
    const float* cross_W = (const float*)d_in[14];
    const float* cross_b = (const float*)d_in[15];
    const int* n1p = (const int*)d_in[16];
    const int* n2p = (const int*)d_in[17];
    const int* taup = (const int*)d_in[20];
    const float* cross_Wb = cross_W + (size_t)2048 * 2048;   // bottom half rows

    float* S = (float*)d_out;                       // [64,256,256]
    const long long NBIG = 16384LL * 2048;          // full [B*N, 2048] buffer elems
    float* E1   = (float*)d_ws;
    float* E2   = E1 + NBIG;
    float* rcs1 = E2 + NBIG;                        // [16384]
    float* rcs2 = rcs1 + 16384;
    float* Ha   = rcs2 + 16384;

    // Chunk size (batches per chunk), power of two <= 32, sized from ws_size.
    // Footprint: 2 full buffers + rcs + 2 * (nb * 256 * 2048) floats.
    int nb = 1;
    {
        const size_t base = ((size_t)(2 * NBIG) + 32768) * 4;
        if (ws_size > base) {
            const long long remf = (long long)((ws_size - base) / 4);
            const long long maxb = remf / (2LL * 524288);
            nb = 32;
            while (nb > 1 && (long long)nb > maxb) nb >>= 1;
        }
    }
    float* Hb = Ha + (size_t)nb * 524288;
    const int nc = 64 / nb;                         // chunks
    const long long cpy4 = (long long)nb * 131072;  // float4s per chunk buffer

    const dim3 blk(256);
    const dim3 gRow(16, nb * 2, 1);   // [nb*256 x 2048] row-local GEMM
    const dim3 gBat(16, 2, nb);       // [256 x 2048] x nb batched
    const dim3 gS(2, 2, nb);          // [256 x 256]  x nb batched

    colsum_rcp_k<<<64, 256, 0, stream>>>(A1, rcs1);
    colsum_rcp_k<<<64, 256, 0, stream>>>(A2, rcs2);

    // ---- layer 0 Gconv: Eg = Ag @ (rcs_g * relu(f_g@aW+ab)) + relu(f_g@uW+ub)
    for (int c = 0; c < nc; ++c) {
        const long long ro = (long long)c * nb * 256;   // row offset
        const long long bo = (long long)c * nb;         // batch offset
        const float* fs[2] = { feat1, feat2 };
        const float* As_[2] = { A1, A2 };
        const float* rc[2] = { rcs1, rcs2 };
        float* Es[2] = { E1, E2 };
        for (int g = 0; g < 2; ++g) {
            sgemm_k<false,false,EPI_BIAS_RELU_SCALE><<<gRow, blk, 0, stream>>>(
                fs[g] + ro * 1024, g0_aW, Ha, nb * 256, 2048, 1024, 0,0,0,
                g0_ab, rc[g] + ro, n1p, n2p, taup);
            sgemm_k<false,false,EPI_BIAS_RELU><<<gRow, blk, 0, stream>>>(
                fs[g] + ro * 1024, g0_uW, Es[g] + ro * 2048, nb * 256, 2048, 1024, 0,0,0,
                g0_ub, nullptr, n1p, n2p, taup);
            sgemm_k<false,false,EPI_ADD><<<gBat, blk, 0, stream>>>(
                As_[g] + bo * 65536, Ha, Es[g] + ro * 2048, 256, 2048, 256,
                65536, 524288, 524288, nullptr, nullptr, n1p, n2p, taup);
        }
    }

    // ---- affinity 0: S = mask((E1@aff0_W) @ E2^T / tau)
    for (int c = 0; c < nc; ++c) {
        const long long ro = (long long)c * nb * 256, bo = (long long)c * nb;
        sgemm_k<false,false,EPI_STORE><<<gRow, blk, 0, stream>>>(
            E1 + ro * 2048, aff0_W, Ha, nb * 256, 2048, 2048, 0,0,0,
            nullptr, nullptr, n1p, n2p, taup);
        sgemm_k<false,true,EPI_MASK_TAU><<<gS, blk, 0, stream>>>(
            Ha, E2 + ro * 2048, S + bo * 65536, 256, 256, 2048,
            524288, 524288, 65536, nullptr, nullptr, n1p + bo, n2p + bo, taup);
    }
    for (int it = 0; it < 5; ++it) {   // sk_max_iter = 10
        sk_row_k<<<4096, 256, 0, stream>>>(S, n1p);
        sk_col_k<<<64, 1024, 0, stream>>>(S, n2p);
    }
    sk_exp_k<<<16384, 256, 0, stream>>>(S, n1p, n2p);

    // ---- cross update (batch-local):
    //  NE1 = E1@Wt + (S @E2)@Wb + b -> back into E1
    //  NE2 = E2@Wt + (S^T@E1)@Wb + b -> back into E2
    for (int c = 0; c < nc; ++c) {
        const long long ro = (long long)c * nb * 256, bo = (long long)c * nb;
        float* e1c = E1 + ro * 2048;
        float* e2c = E2 + ro * 2048;
        sgemm_k<false,false,EPI_STORE><<<gBat, blk, 0, stream>>>(
            S + bo * 65536, e2c, Ha, 256, 2048, 256, 65536, 524288, 524288,
            nullptr, nullptr, n1p, n2p, taup);
        sgemm_k<false,false,EPI_BIAS><<<gRow, blk, 0, stream>>>(
            e1c, cross_W, Hb, nb * 256, 2048, 2048, 0,0,0,
            cross_b, nullptr, n1p, n2p, taup);
        sgemm_k<false,false,EPI_ADD><<<gRow, blk, 0, stream>>>(
            Ha, cross_Wb, Hb, nb * 256, 2048, 2048, 0,0,0,
            nullptr, nullptr, n1p, n2p, taup);
        sgemm_k<true,false,EPI_STORE><<<gBat, blk, 0, stream>>>(
            S + bo * 65536, e1c, Ha, 256, 2048, 256, 65536, 524288, 524288,
            nullptr, nullptr, n1p, n2p, taup);
        copy4_k<<<2048, 256, 0, stream>>>((const float4*)Hb, (float4*)e1c, cpy4);
        sgemm_k<false,false,EPI_BIAS><<<gRow, blk, 0, stream>>>(
            e2c, cross_W, Hb, nb * 256, 2048, 2048, 0,0,0,
            cross_b, nullptr, n1p, n2p, taup);
        sgemm_k<false,false,EPI_ADD><<<gRow, blk, 0, stream>>>(
            Ha, cross_Wb, Hb, nb * 256, 2048, 2048, 0,0,0,
            nullptr, nullptr, n1p, n2p, taup);
        copy4_k<<<2048, 256, 0, stream>>>((const float4*)Hb, (float4*)e2c, cpy4);
    }

    // ---- layer 1 Gconv (inputs NE1 in E1, NE2 in E2; outputs back in place)
    for (int c = 0; c < nc; ++c) {
        const long long ro = (long long)c * nb * 256, bo = (long long)c * nb;
        const float* As_[2] = { A1, A2 };
        const float* rc[2] = { rcs1, rcs2 };
        float* Es[2] = { E1, E2 };
        for (int g = 0; g < 2; ++g) {
            float* ec = Es[g] + ro * 2048;
            sgemm_k<false,false,EPI_BIAS_RELU_SCALE><<<gRow, blk, 0, stream>>>(
                ec, g1_aW, Ha, nb * 256, 2048, 2048, 0,0,0,
                g1_ab, rc[g] + ro, n1p, n2p, taup);
            sgemm_k<false,false,EPI_BIAS_RELU><<<gRow, blk, 0, stream>>>(
                ec, g1_uW, Hb, nb * 256, 2048, 2048, 0,0,0,
                g1_ub, nullptr, n1p, n2p, taup);
            sgemm_k<false,false,EPI_ADD><<<gBat, blk, 0, stream>>>(
                As_[g] + bo * 65536, Ha, Hb, 256, 2048, 256,
                65536, 524288, 524288, nullptr, nullptr, n1p, n2p, taup);
            copy4_k<<<2048, 256, 0, stream>>>((const float4*)Hb, (float4*)ec, cpy4);
        }
    }

    // ---- affinity 1 + final sinkhorn -> d_out
    for (int c = 0; c < nc; ++c) {
        const long long ro = (long long)c * nb * 256, bo = (long long)c * nb;
        sgemm_k<false,false,EPI_STORE><<<gRow, blk, 0, stream>>>(
            E1 + ro * 2048, aff1_W, Ha, nb * 256, 2048, 2048, 0,0,0,
            nullptr, nullptr, n1p, n2p, taup);
        sgemm_k<false,true,EPI_MASK_TAU><<<gS, blk, 0, stream>>>(
            Ha, E2 + ro * 2048, S + bo * 65536, 256, 256, 2048,
            524288, 524288, 65536, nullptr, nullptr, n1p + bo, n2p + bo, taup);
    }
    for (int it = 0; it < 5; ++it) {
        sk_row_k<<<4096, 256, 0, stream>>>(S, n1p);
        sk_col_k<<<64, 1024, 0, stream>>>(S, n2p);
    }
    sk_exp_k<<<16384, 256, 0, stream>>>(S, n1p, n2p);
}

// Round 4
// 6311.208 us; speedup vs baseline: 23.2919x; 23.2919x over previous
//
#include <hip/hip_runtime.h>
#include <cstdint>
#include <cstddef>

typedef __bf16 bf16;
typedef float f32x4 __attribute__((ext_vector_type(4)));
typedef bf16  bf16x8 __attribute__((ext_vector_type(8)));

#define NEGV (-1e30f)

// B=64, N=256, IN=1024, HID=OUT=2048, BN=16384
enum { EPI_STORE = 0, EPI_ADD = 1, EPI_BIAS_RELU = 2, EPI_BIAS = 3,
       EPI_MASK_TAU = 4, EPI_STORE_T = 5, EPI_BIAS_RELU_SCALE_T = 6 };

__device__ __forceinline__ void gload16(const void* g, void* l) {
    __builtin_amdgcn_global_load_lds((const __attribute__((address_space(1))) void*)g,
                                     (__attribute__((address_space(3))) void*)l, 16, 0, 0);
}

// bf16 MFMA GEMM (m97 structure): C[bz] = epi(A[bz] @ B[bz]^T-layout)
// A: [M][K] bf16 row-major.  B: NT layout [N][K] bf16 row-major.
// 128x128 C-tile, BK=32, 256 thr = 4 waves (2x2 of 64x64), mfma_f32_16x16x32_bf16.
// M,N multiples of 128; K multiple of 32.
// T-epilogues write C per-256-row-batch transposed: CT[b][n][m] (b = gm>>8, stride 2048*256).
template<int EPI, typename CT>
__global__ __launch_bounds__(256, 2)
void hgemm_k(const bf16* __restrict__ Ab, const bf16* __restrict__ Bb,
             CT* __restrict__ Cb, const int M, const int N, const int K,
             const long long sA, const long long sB, const long long sC,
             const float* __restrict__ bias, const float* __restrict__ rowscale,
             const int* __restrict__ n1p, const int* __restrict__ n2p,
             const int* __restrict__ taup)
{
    __shared__ bf16 Asl[128 * 32];
    __shared__ bf16 Bsl[128 * 32];
    const int bz = blockIdx.z;
    const bf16* __restrict__ A = Ab + (size_t)bz * (size_t)sA;
    const bf16* __restrict__ B = Bb + (size_t)bz * (size_t)sB;
    CT* __restrict__ C = Cb + (size_t)bz * (size_t)sC;
    const int m0 = blockIdx.y * 128, n0 = blockIdx.x * 128;
    const int tid = (int)threadIdx.x;
    const int lane = tid & 63, wave = tid >> 6;
    const int wm = (wave & 1) * 64, wn = (wave >> 1) * 64;
    const int lrow = lane & 15, quad = lane >> 4;

    f32x4 acc[4][4];
    const f32x4 zero = {0.f, 0.f, 0.f, 0.f};
#pragma unroll
    for (int i = 0; i < 4; ++i)
#pragma unroll
        for (int j = 0; j < 4; ++j) acc[i][j] = zero;

    // staging: thread tid loads 16B -> LDS offset tid*16 (lane-order-contiguous law)
    const int sr = tid >> 2, sck = (tid & 3) * 8;
    const bf16* ga0 = A + (size_t)(m0 + sr) * K + sck;
    const bf16* ga1 = A + (size_t)(m0 + 64 + sr) * K + sck;
    const bf16* gb0 = B + (size_t)(n0 + sr) * K + sck;
    const bf16* gb1 = B + (size_t)(n0 + 64 + sr) * K + sck;
    bf16* la0 = Asl + tid * 8;
    bf16* la1 = Asl + 2048 + tid * 8;
    bf16* lb0 = Bsl + tid * 8;
    bf16* lb1 = Bsl + 2048 + tid * 8;
    const bf16* ar = Asl + (wm + lrow) * 32 + quad * 8;
    const bf16* br = Bsl + (wn + lrow) * 32 + quad * 8;

    for (int k0 = 0; k0 < K; k0 += 32) {
        gload16(ga0, la0); gload16(ga1, la1);
        gload16(gb0, lb0); gload16(gb1, lb1);
        ga0 += 32; ga1 += 32; gb0 += 32; gb1 += 32;
        __syncthreads();
        bf16x8 af[4], bfr[4];
#pragma unroll
        for (int t = 0; t < 4; ++t) {
            af[t]  = *(const bf16x8*)(ar + t * 512);
            bfr[t] = *(const bf16x8*)(br + t * 512);
        }
#pragma unroll
        for (int i = 0; i < 4; ++i)
#pragma unroll
            for (int j = 0; j < 4; ++j)
                acc[i][j] = __builtin_amdgcn_mfma_f32_16x16x32_bf16(af[i], bfr[j], acc[i][j], 0, 0, 0);
        __syncthreads();
    }

    // C/D layout: col = lane&15, row = quad*4 + reg   [m89-verified]
    if constexpr (EPI == EPI_STORE_T || EPI == EPI_BIAS_RELU_SCALE_T) {
        // transposed per-batch write, packed 4x bf16 (8B) along m
#pragma unroll
        for (int ti = 0; ti < 4; ++ti) {
            const int gm0 = m0 + wm + ti * 16 + quad * 4;   // 4 consecutive rows
#pragma unroll
            for (int tj = 0; tj < 4; ++tj) {
                const int gn = n0 + wn + tj * 16 + lrow;
                union { bf16 h[4]; uint2 u; } p;
#pragma unroll
                for (int r = 0; r < 4; ++r) {
                    float v = acc[ti][tj][r];
                    if constexpr (EPI == EPI_BIAS_RELU_SCALE_T)
                        v = fmaxf(v + bias[gn], 0.f) * rowscale[gm0 + r];
                    p.h[r] = (bf16)v;
                }
                *(uint2*)((bf16*)C + ((size_t)(gm0 >> 8)) * 524288 +
                          (size_t)gn * 256 + (gm0 & 255)) = p.u;
            }
        }
        return;
    }

    int n1b = 0, n2b = 0; float tauv = 1.f;
    if constexpr (EPI == EPI_MASK_TAU) { n1b = n1p[bz]; n2b = n2p[bz]; tauv = (float)taup[0]; }
#pragma unroll
    for (int ti = 0; ti < 4; ++ti) {
        const int gm0 = m0 + wm + ti * 16 + quad * 4;
#pragma unroll
        for (int r = 0; r < 4; ++r) {
            const int gm = gm0 + r;
#pragma unroll
            for (int tj = 0; tj < 4; ++tj) {
                const int gn = n0 + wn + tj * 16 + lrow;
                const float v = acc[ti][tj][r];
                CT* cp = C + (size_t)gm * N + gn;
                if constexpr (EPI == EPI_STORE)          *cp = (CT)v;
                else if constexpr (EPI == EPI_ADD)       *cp = (CT)((float)*cp + v);
                else if constexpr (EPI == EPI_BIAS_RELU) *cp = (CT)fmaxf(v + bias[gn], 0.f);
                else if constexpr (EPI == EPI_BIAS)      *cp = (CT)(v + bias[gn]);
                else *cp = (CT)((gm < n1b && gn < n2b) ? v / tauv : NEGV);
            }
        }
    }
}

// fp32 [K][N] -> bf16 [N][K]  (weight transpose-convert)
__global__ __launch_bounds__(256)
void wtrans_k(const float* __restrict__ W, bf16* __restrict__ Wt, const int K, const int N)
{
    __shared__ float tl[32][33];
    const int k0 = blockIdx.y * 32, n0 = blockIdx.x * 32;
    const int tx = (int)threadIdx.x & 31, ty = (int)threadIdx.x >> 5;
#pragma unroll
    for (int q = 0; q < 4; ++q)
        tl[ty + 8 * q][tx] = W[(size_t)(k0 + ty + 8 * q) * N + n0 + tx];
    __syncthreads();
#pragma unroll
    for (int q = 0; q < 4; ++q)
        Wt[(size_t)(n0 + ty + 8 * q) * K + k0 + tx] = (bf16)tl[tx][ty + 8 * q];
}

// fp32 -> bf16 elementwise (vectorized)
__global__ __launch_bounds__(256)
void cvt_k(const float4* __restrict__ in, uint2* __restrict__ out, const long long n4)
{
    long long i = (long long)blockIdx.x * 256 + threadIdx.x;
    const long long st = (long long)gridDim.x * 256;
    for (; i < n4; i += st) {
        const float4 v = in[i];
        union { bf16 h[4]; uint2 u; } p;
        p.h[0] = (bf16)v.x; p.h[1] = (bf16)v.y; p.h[2] = (bf16)v.z; p.h[3] = (bf16)v.w;
        out[i] = p.u;
    }
}

// S fp32 [64][256][256] -> Sb bf16 (same layout) + Stb bf16 (per-batch transpose)
__global__ __launch_bounds__(256)
void sconv_k(const float* __restrict__ S, bf16* __restrict__ Sb, bf16* __restrict__ Stb)
{
    __shared__ float tl[64][68];
    const int b = blockIdx.z, r0 = blockIdx.y * 64, c0 = blockIdx.x * 64;
    const float* I = S + (size_t)b * 65536;
    const int t = (int)threadIdx.x, lr = t >> 2, lc = (t & 3) * 16;
    const float* ip = I + (size_t)(r0 + lr) * 256 + c0 + lc;
    union { bf16 h[8]; uint4 u; } p0, p1;
#pragma unroll
    for (int q = 0; q < 4; ++q) {
        const float4 v = *(const float4*)(ip + 4 * q);
        *(float4*)&tl[lr][lc + 4 * q] = v;
        bf16* hh = (q < 2) ? (p0.h + 4 * q) : (p1.h + 4 * (q - 2));
        hh[0] = (bf16)v.x; hh[1] = (bf16)v.y; hh[2] = (bf16)v.z; hh[3] = (bf16)v.w;
    }
    bf16* sbp = Sb + (size_t)b * 65536 + (size_t)(r0 + lr) * 256 + c0 + lc;
    *(uint4*)sbp = p0.u; *(uint4*)(sbp + 8) = p1.u;
    __syncthreads();
    union { bf16 h[8]; uint4 u; } q0, q1;
#pragma unroll
    for (int j = 0; j < 8; ++j) {
        q0.h[j] = (bf16)tl[lc + j][lr];
        q1.h[j] = (bf16)tl[lc + 8 + j][lr];
    }
    bf16* stp = Stb + (size_t)b * 65536 + (size_t)(c0 + lr) * 256 + r0 + lc;
    *(uint4*)stp = q0.u; *(uint4*)(stp + 8) = q1.u;
}

// rcs[b,j] = 1 / max(sum_i |A[b,i,j]|, 1e-12)
__global__ __launch_bounds__(256)
void colsum_rcp_k(const float* __restrict__ A, float* __restrict__ rcs)
{
    const int b = blockIdx.x, j = (int)threadIdx.x;
    const float* p = A + (size_t)b * 65536;
    float s = 0.f;
    for (int i = 0; i < 256; ++i) s += fabsf(p[i * 256 + j]);
    rcs[b * 256 + j] = 1.f / fmaxf(s, 1e-12f);
}

// Row logsumexp pass: one 64-lane wave per row.
__global__ __launch_bounds__(256)
void sk_row_k(float* __restrict__ S, const int* __restrict__ n1p)
{
    const int w = (int)threadIdx.x >> 6, lane = (int)threadIdx.x & 63;
    const int rowg = blockIdx.x * 4 + w;
    const int b = rowg >> 8, i = rowg & 255;
    float* p = S + (size_t)rowg * 256;
    float4 v = ((const float4*)p)[lane];
    float m = fmaxf(fmaxf(v.x, v.y), fmaxf(v.z, v.w));
#pragma unroll
    for (int off = 32; off > 0; off >>= 1) m = fmaxf(m, __shfl_down(m, off));
    m = __shfl(m, 0);
    float s = expf(v.x - m) + expf(v.y - m) + expf(v.z - m) + expf(v.w - m);
#pragma unroll
    for (int off = 32; off > 0; off >>= 1) s += __shfl_down(s, off);
    s = __shfl(s, 0);
    const float lse = m + logf(s);
    if (i < n1p[b]) {
        v.x -= lse; v.y -= lse; v.z -= lse; v.w -= lse;
        ((float4*)p)[lane] = v;
    }
}

// Column logsumexp pass: one 1024-thr block per batch matrix.
__global__ __launch_bounds__(1024)
void sk_col_k(float* __restrict__ S, const int* __restrict__ n2p)
{
    __shared__ float Ms[4][256], Ss[4][256], Ls[256];
    const int b = blockIdx.x;
    const int j = (int)threadIdx.x & 255, q = (int)threadIdx.x >> 8;
    float* base = S + (size_t)b * 65536;
    float m = -3.0e38f;
    for (int i = q * 64; i < q * 64 + 64; ++i) m = fmaxf(m, base[i * 256 + j]);
    float s = 0.f;
    for (int i = q * 64; i < q * 64 + 64; ++i) s += expf(base[i * 256 + j] - m);
    Ms[q][j] = m; Ss[q][j] = s;
    __syncthreads();
    if (q == 0) {
        const float m0 = Ms[0][j], m1 = Ms[1][j], m2 = Ms[2][j], m3 = Ms[3][j];
        const float mm = fmaxf(fmaxf(m0, m1), fmaxf(m2, m3));
        const float ss = Ss[0][j] * expf(m0 - mm) + Ss[1][j] * expf(m1 - mm) +
                         Ss[2][j] * expf(m2 - mm) + Ss[3][j] * expf(m3 - mm);
        Ls[j] = mm + logf(ss);
    }
    __syncthreads();
    if (j < n2p[b]) {
        const float lse = Ls[j];
        for (int i = q * 64; i < q * 64 + 64; ++i) base[i * 256 + j] -= lse;
    }
}

__global__ __launch_bounds__(256)
void sk_exp_k(float* __restrict__ S, const int* __restrict__ n1p,
              const int* __restrict__ n2p)
{
    const size_t idx = (size_t)blockIdx.x * 256 + threadIdx.x;
    const int b = (int)(idx >> 16);
    const int i = (int)((idx >> 8) & 255), j = (int)(idx & 255);
    const float v = S[idx];
    S[idx] = (i < n1p[b] && j < n2p[b]) ? expf(v) : 0.f;
}

extern "C" void kernel_launch(void* const* d_in, const int* in_sizes, int n_in,
                              void* d_out, int out_size, void* d_ws, size_t ws_size,
                              hipStream_t stream)
{
    (void)in_sizes; (void)n_in; (void)out_size;
    const float* feat1  = (const float*)d_in[0];
    const float* feat2  = (const float*)d_in[1];
    const float* A1     = (const float*)d_in[2];
    const float* A2     = (const float*)d_in[3];
    const float* g0_aW  = (const float*)d_in[4];
    const float* g0_ab  = (const float*)d_in[5];
    const float* g0_uW  = (const float*)d_in[6];
    const float* g0_ub  = (const float*)d_in[7];
    const float* g1_aW  = (const float*)d_in[8];
    const float* g1_ab  = (const float*)d_in[9];
    const float* g1_uW  = (const float*)d_in[10];
    const float* g1_ub  = (const float*)d_in[11];
    const float* aff0_W = (const float*)d_in[12];
    const float* aff1_W = (const float*)d_in[13];
    const float* cross_W = (const float*)d_in[14];
    const float* cross_b = (const float*)d_in[15];
    const int* n1p = (const int*)d_in[16];
    const int* n2p = (const int*)d_in[17];
    const int* taup = (const int*)d_in[20];

    float* S = (float*)d_out;                     // [64,256,256] fp32 (sinkhorn in place)
    // ---- workspace layout (base = 226,623,488 B), chunk scratch adapts to ws_size
    bf16* w = (bf16*)d_ws;
    bf16* E1b = w;    w += 33554432;              // [16384][2048]
    bf16* E2b = w;    w += 33554432;
    bf16* g0aWt = w;  w += 2097152;               // [2048][1024]
    bf16* g0uWt = w;  w += 2097152;
    bf16* g1aWt = w;  w += 4194304;               // [2048][2048]
    bf16* g1uWt = w;  w += 4194304;
    bf16* aff0Wt = w; w += 4194304;
    bf16* aff1Wt = w; w += 4194304;
    bf16* cWtT = w;   w += 4194304;               // cross_W rows 0..2047, transposed
    bf16* cWbT = w;   w += 4194304;               // cross_W rows 2048..4095, transposed
    bf16* A1b = w;    w += 4194304;               // [64][256][256]
    bf16* A2b = w;    w += 4194304;
    bf16* Sb  = w;    w += 4194304;
    bf16* Stb = w;    w += 4194304;
    float* rcs1 = (float*)w;                      // [16384]
    float* rcs2 = rcs1 + 16384;

    // chunk size nb (batches per chunk): base + nb*3,670,016 B must fit ws_size
    int nb = 1;
    {
        const long long avail = (long long)ws_size - 226623488LL;
        while (nb < 32 && (long long)(nb * 2) * 3670016LL <= avail) nb <<= 1;
    }
    bf16* Ha  = (bf16*)(rcs2 + 16384);            // [nb][2048][256] or [nb*256][2048]
    bf16* Hb  = Ha + (size_t)nb * 524288;         // [nb*256][2048]
    bf16* Hc  = Hb + (size_t)nb * 524288;
    bf16* Fbc = Hc + (size_t)nb * 524288;         // [nb*256][1024]
    const int nc = 64 / nb;

    const dim3 blk(256);
    const dim3 gRow(16, nb * 2, 1);   // [nb*256 x 2048] chunked row GEMM
    const dim3 gBat(16, 2, nb);       // [256 x 2048] x nb batched
    const dim3 gSS(2, 2, nb);         // [256 x 256] x nb batched

    // ---- prep
    wtrans_k<<<dim3(64, 32), blk, 0, stream>>>(g0_aW, g0aWt, 1024, 2048);
    wtrans_k<<<dim3(64, 32), blk, 0, stream>>>(g0_uW, g0uWt, 1024, 2048);
    wtrans_k<<<dim3(64, 64), blk, 0, stream>>>(g1_aW, g1aWt, 2048, 2048);
    wtrans_k<<<dim3(64, 64), blk, 0, stream>>>(g1_uW, g1uWt, 2048, 2048);
    wtrans_k<<<dim3(64, 64), blk, 0, stream>>>(aff0_W, aff0Wt, 2048, 2048);
    wtrans_k<<<dim3(64, 64), blk, 0, stream>>>(aff1_W, aff1Wt, 2048, 2048);
    wtrans_k<<<dim3(64, 64), blk, 0, stream>>>(cross_W, cWtT, 2048, 2048);
    wtrans_k<<<dim3(64, 64), blk, 0, stream>>>(cross_W + 4194304, cWbT, 2048, 2048);
    cvt_k<<<1024, blk, 0, stream>>>((const float4*)A1, (uint2*)A1b, 1048576);
    cvt_k<<<1024, blk, 0, stream>>>((const float4*)A2, (uint2*)A2b, 1048576);
    colsum_rcp_k<<<64, blk, 0, stream>>>(A1, rcs1);
    colsum_rcp_k<<<64, blk, 0, stream>>>(A2, rcs2);

    // ---- layer 0 Gconv + affinity 0 (chunked)
    for (int c = 0; c < nc; ++c) {
        const long long bo = (long long)c * nb;
        const float* fs[2]  = { feat1, feat2 };
        const bf16*  Ab[2]  = { A1b, A2b };
        const float* rc[2]  = { rcs1, rcs2 };
        bf16*        Es[2]  = { E1b, E2b };
        for (int g = 0; g < 2; ++g) {
            bf16* ec = Es[g] + bo * 524288;
            cvt_k<<<1024, blk, 0, stream>>>(
                (const float4*)(fs[g] + bo * 262144), (uint2*)Fbc, (long long)nb * 65536);
            hgemm_k<EPI_BIAS_RELU_SCALE_T, bf16><<<gRow, blk, 0, stream>>>(   // axT -> Ha
                Fbc, g0aWt, Ha, nb * 256, 2048, 1024, 0, 0, 0,
                g0_ab, rc[g] + bo * 256, nullptr, nullptr, nullptr);
            hgemm_k<EPI_BIAS_RELU, bf16><<<gRow, blk, 0, stream>>>(           // E = relu(f@uW+b)
                Fbc, g0uWt, ec, nb * 256, 2048, 1024, 0, 0, 0,
                g0_ub, nullptr, nullptr, nullptr, nullptr);
            hgemm_k<EPI_ADD, bf16><<<gBat, blk, 0, stream>>>(                 // E += A @ ax
                Ab[g] + bo * 65536, Ha, ec, 256, 2048, 256,
                65536, 524288, 524288, nullptr, nullptr, nullptr, nullptr, nullptr);
        }
        hgemm_k<EPI_STORE, bf16><<<gRow, blk, 0, stream>>>(                   // P = E1@aff0W
            E1b + bo * 524288, aff0Wt, Ha, nb * 256, 2048, 2048, 0, 0, 0,
            nullptr, nullptr, nullptr, nullptr, nullptr);
        hgemm_k<EPI_MASK_TAU, float><<<gSS, blk, 0, stream>>>(                // S = mask(P@E2^T/tau)
            Ha, E2b + bo * 524288, S + bo * 65536, 256, 256, 2048,
            524288, 524288, 65536, nullptr, nullptr, n1p + bo, n2p + bo, taup);
    }
    for (int it = 0; it < 5; ++it) {              // sk_max_iter = 10
        sk_row_k<<<4096, blk, 0, stream>>>(S, n1p);
        sk_col_k<<<64, 1024, 0, stream>>>(S, n2p);
    }
    sk_exp_k<<<16384, blk, 0, stream>>>(S, n1p, n2p);
    sconv_k<<<dim3(4, 4, 64), blk, 0, stream>>>(S, Sb, Stb);

    // ---- cross update + layer 1 + affinity 1 (chunked; U@cWb reassociated as S@(E@cWb))
    for (int c = 0; c < nc; ++c) {
        const long long bo = (long long)c * nb;
        bf16* e1c = E1b + bo * 524288;
        bf16* e2c = E2b + bo * 524288;
        // NE1 = E1@cWt + S@(E2@cWb) + b  -> Hb
        hgemm_k<EPI_STORE_T, bf16><<<gRow, blk, 0, stream>>>(
            e2c, cWbT, Ha, nb * 256, 2048, 2048, 0, 0, 0, nullptr, nullptr, nullptr, nullptr, nullptr);
        hgemm_k<EPI_BIAS, bf16><<<gRow, blk, 0, stream>>>(
            e1c, cWtT, Hb, nb * 256, 2048, 2048, 0, 0, 0, cross_b, nullptr, nullptr, nullptr, nullptr);
        hgemm_k<EPI_ADD, bf16><<<gBat, blk, 0, stream>>>(
            Sb + bo * 65536, Ha, Hb, 256, 2048, 256, 65536, 524288, 524288,
            nullptr, nullptr, nullptr, nullptr, nullptr);
        // NE2 = E2@cWt + S^T@(E1@cWb) + b  -> Hc
        hgemm_k<EPI_STORE_T, bf16><<<gRow, blk, 0, stream>>>(
            e1c, cWbT, Ha, nb * 256, 2048, 2048, 0, 0, 0, nullptr, nullptr, nullptr, nullptr, nullptr);
        hgemm_k<EPI_BIAS, bf16><<<gRow, blk, 0, stream>>>(
            e2c, cWtT, Hc, nb * 256, 2048, 2048, 0, 0, 0, cross_b, nullptr, nullptr, nullptr, nullptr);
        hgemm_k<EPI_ADD, bf16><<<gBat, blk, 0, stream>>>(
            Stb + bo * 65536, Ha, Hc, 256, 2048, 256, 65536, 524288, 524288,
            nullptr, nullptr, nullptr, nullptr, nullptr);
        // layer 1 graph 1: E1 = A1@(rcs1*relu(NE1@aW+b)) + relu(NE1@uW+b)
        hgemm_k<EPI_BIAS_RELU_SCALE_T, bf16><<<gRow, blk, 0, stream>>>(
            Hb, g1aWt, Ha, nb * 256, 2048, 2048, 0, 0, 0,
            g1_ab, rcs1 + bo * 256, nullptr, nullptr, nullptr);
        hgemm_k<EPI_BIAS_RELU, bf16><<<gRow, blk, 0, stream>>>(
            Hb, g1uWt, e1c, nb * 256, 2048, 2048, 0, 0, 0, g1_ub, nullptr, nullptr, nullptr, nullptr);
        hgemm_k<EPI_ADD, bf16><<<gBat, blk, 0, stream>>>(
            A1b + bo * 65536, Ha, e1c, 256, 2048, 256, 65536, 524288, 524288,
            nullptr, nullptr, nullptr, nullptr, nullptr);
        // layer 1 graph 2
        hgemm_k<EPI_BIAS_RELU_SCALE_T, bf16><<<gRow, blk, 0, stream>>>(
            Hc, g1aWt, Ha, nb * 256, 2048, 2048, 0, 0, 0,
            g1_ab, rcs2 + bo * 256, nullptr, nullptr, nullptr);
        hgemm_k<EPI_BIAS_RELU, bf16><<<gRow, blk, 0, stream>>>(
            Hc, g1uWt, e2c, nb * 256, 2048, 2048, 0, 0, 0, g1_ub, nullptr, nullptr, nullptr, nullptr);
        hgemm_k<EPI_ADD, bf16><<<gBat, blk, 0, stream>>>(
            A2b + bo * 65536, Ha, e2c, 256, 2048, 256, 65536, 524288, 524288,
            nullptr, nullptr, nullptr, nullptr, nullptr);
        // affinity 1
        hgemm_k<EPI_STORE, bf16><<<gRow, blk, 0, stream>>>(
            e1c, aff1Wt, Ha, nb * 256, 2048, 2048, 0, 0, 0,
            nullptr, nullptr, nullptr, nullptr, nullptr);
        hgemm_k<EPI_MASK_TAU, float><<<gSS, blk, 0, stream>>>(
            Ha, e2c, S + bo * 65536, 256, 256, 2048, 524288, 524288, 65536,
            nullptr, nullptr, n1p + bo, n2p + bo, taup);
    }
    for (int it = 0; it < 5; ++it) {
        sk_row_k<<<4096, blk, 0, stream>>>(S, n1p);
        sk_col_k<<<64, 1024, 0, stream>>>(S, n2p);
    }
    sk_exp_k<<<16384, blk, 0, stream>>>(S, n1p, n2p);
}